// Round 12
// baseline (250.489 us; speedup 1.0000x reference)
//
#include <hip/hip_runtime.h>

#define NNODES 50000
#define NEDGES 800000
#define HDIM 64
#define CAP 64
#define GAMMA 0.2f
#define SCAN_B 256
#define SCAN_NB ((NNODES + SCAN_B - 1) / SCAN_B)   // 196
#define LOSS_GRID 2048
#define NPART 8
#define PART_DIV 6272                               // ceil-ish: 8*6272 >= 50000, d/6272 in 0..7
#define E4 (NEDGES / 4)                             // 200000 int4 chunks
#define NWAVES_B1 512
#define CHUNK_W ((E4 + NWAVES_B1 - 1) / NWAVES_B1)  // 391 int4s per wave
#define BCAP 512                                    // per-(wave,part) region capacity

typedef unsigned short u16;
typedef unsigned int u32;
typedef unsigned long long u64;

__device__ __forceinline__ u16 f2bf(float f) {
    u32 u = __float_as_uint(f);
    u32 r = (u + 0x7FFFu + ((u >> 16) & 1u)) >> 16;   // round-to-nearest-even
    return (u16)r;
}
__device__ __forceinline__ float bflo(u32 u) { return __uint_as_float(u << 16); }
__device__ __forceinline__ float bfhi(u32 u) { return __uint_as_float(u & 0xFFFF0000u); }

__device__ __forceinline__ float wave_sum(float v) {
    #pragma unroll
    for (int off = 32; off; off >>= 1) v += __shfl_xor(v, off, 64);
    return v;
}
__device__ __forceinline__ float wave_max(float v) {
    #pragma unroll
    for (int off = 32; off; off >>= 1) v = fmaxf(v, __shfl_xor(v, off, 64));
    return v;
}
__device__ __forceinline__ int wave_sum_i(int v) {
    #pragma unroll
    for (int off = 32; off; off >>= 1) v += __shfl_xor(v, off, 64);
    return v;
}
__device__ __forceinline__ float group8_sum(float v) {
    v += __shfl_xor(v, 1, 64);
    v += __shfl_xor(v, 2, 64);
    v += __shfl_xor(v, 4, 64);
    return v;
}

// ws[k] = sum_j W_fc[j,k]*a_src[j]; wd[k] = sum_j W_fc[j,k]*a_dst[j]
__global__ void k_wswd(const float* __restrict__ Wfc, const float* __restrict__ attn,
                       float* __restrict__ ws, float* __restrict__ wd) {
    int t = threadIdx.x;  // 128 threads
    int k = t & 63;
    const float* av = attn + ((t >= 64) ? HDIM : 0);
    float s = 0.f;
    for (int j = 0; j < HDIM; ++j) s += Wfc[j * HDIM + k] * av[j];
    if (t < 64) ws[k] = s; else wd[k] = s;
}

// Pass 1: bin edges by dst partition into per-(wave,part) private regions.
// No atomics: ballot/rank aggregation with register cursors; rank-coalesced stores.
__global__ __launch_bounds__(256) void k_bucket(const int4* __restrict__ src4,
                                                const int4* __restrict__ dst4,
                                                u32* __restrict__ region,
                                                int* __restrict__ cnt_out) {
    const int wid = (blockIdx.x * blockDim.x + threadIdx.x) >> 6;   // 0..511
    const int lane = threadIdx.x & 63;
    const u64 below = ((lane == 63) ? ~0ull : ((1ull << (lane + 1)) - 1)) >> 1; // bits < lane
    const int lo = wid * CHUNK_W;
    const int hi = min(lo + CHUNK_W, E4);
    int cur[NPART];
    #pragma unroll
    for (int p = 0; p < NPART; ++p) cur[p] = 0;

    for (int base = lo; base < hi; base += 64) {
        int i = base + lane;
        bool have = i < hi;
        int4 s4 = have ? src4[i] : make_int4(0, 0, 0, 0);
        int4 d4 = have ? dst4[i] : make_int4(0, 0, 0, 0);
        #pragma unroll
        for (int k = 0; k < 4; ++k) {
            int s = (k == 0) ? s4.x : (k == 1) ? s4.y : (k == 2) ? s4.z : s4.w;
            int d = (k == 0) ? d4.x : (k == 1) ? d4.y : (k == 2) ? d4.z : d4.w;
            int part = have ? (d / PART_DIV) : NPART;   // NPART = no match
            u32 v = (u32)s | ((u32)d << 16);
            #pragma unroll
            for (int p = 0; p < NPART; ++p) {
                u64 m = __ballot(part == p);
                if (m == 0ull) continue;
                if (part == p) {
                    int rank = __popcll(m & below);
                    int pos = cur[p] + rank;
                    if (pos < BCAP) region[((size_t)wid * NPART + p) * BCAP + pos] = v;
                }
                cur[p] += __popcll(m);
            }
        }
    }
    #pragma unroll
    for (int p = 0; p < NPART; ++p)
        if (lane == p) cnt_out[wid * NPART + p] = min(cur[p], BCAP);
}

// Pass 2: partition-local scatter into padded CSR. All cursor/padded lines for a
// partition are touched only by that partition's blocks -> single-XCD L2 locality.
__global__ __launch_bounds__(256) void k_scatter(const u32* __restrict__ region,
                                                 const int* __restrict__ cnt,
                                                 int* __restrict__ cursor,
                                                 u16* __restrict__ padded) {
    const int part = blockIdx.x & (NPART - 1);
    const int j = blockIdx.x >> 3;                  // 0..63
    for (int w = j; w < NWAVES_B1; w += 64) {
        int n = cnt[w * NPART + part];
        const u32* base = &region[((size_t)w * NPART + part) * BCAP];
        for (int i = threadIdx.x; i < n; i += 256) {
            u32 v = base[i];
            int d = (int)(v >> 16);
            int s = (int)(v & 0xFFFFu);
            int pos = atomicAdd(&cursor[d], 1);
            if (pos < CAP) padded[(size_t)d * CAP + pos] = (u16)s;
        }
    }
}

// scan phase 1 (first SCAN_NB blocks) + zinit (emb_bf, zs0/zd0) on the full grid
__global__ __launch_bounds__(256) void k_scan1z(const int* __restrict__ deg,
                                                int* __restrict__ blockSums,
                                                const float* __restrict__ emb,
                                                const float* __restrict__ ws,
                                                const float* __restrict__ wd,
                                                u16* __restrict__ emb_bf,
                                                float* __restrict__ zs, float* __restrict__ zd) {
    int t = threadIdx.x;
    if (blockIdx.x < SCAN_NB) {
        int idx = blockIdx.x * SCAN_B + t;
        int v = (idx < NNODES) ? min(deg[idx], CAP) : 0;
        int wsum = wave_sum_i(v);
        __shared__ int part[4];
        if ((t & 63) == 0) part[t >> 6] = wsum;
        __syncthreads();
        if (t == 0) blockSums[blockIdx.x] = part[0] + part[1] + part[2] + part[3];
    }
    int tid = blockIdx.x * blockDim.x + threadIdx.x;
    int wid = tid >> 6;
    int lane = tid & 63;
    if (wid < NNODES) {
        float v = emb[wid * HDIM + lane];
        emb_bf[wid * HDIM + lane] = f2bf(v);
        float a = wave_sum(v * ws[lane]);
        float b = wave_sum(v * wd[lane]);
        if (lane == 0) { zs[wid] = a; zd[wid] = b; }
    }
}

__global__ __launch_bounds__(SCAN_B) void k_scan2(int* __restrict__ blockSums,
                                                  int* __restrict__ blockOffs) {
    __shared__ int s[SCAN_B];
    int t = threadIdx.x;
    int v = (t < SCAN_NB) ? blockSums[t] : 0;
    s[t] = v;
    __syncthreads();
    for (int off = 1; off < SCAN_B; off <<= 1) {
        int x = (t >= off) ? s[t - off] : 0;
        __syncthreads();
        s[t] += x;
        __syncthreads();
    }
    if (t < SCAN_NB) blockOffs[t] = s[t] - v;   // exclusive
}

__global__ __launch_bounds__(SCAN_B) void k_scan3(const int* __restrict__ deg,
                                                  const int* __restrict__ blockOffs,
                                                  int* __restrict__ row_ptr) {
    __shared__ int s[SCAN_B];
    int t = threadIdx.x;
    int idx = blockIdx.x * SCAN_B + t;
    int v = (idx < NNODES) ? min(deg[idx], CAP) : 0;
    s[t] = v;
    __syncthreads();
    for (int off = 1; off < SCAN_B; off <<= 1) {
        int x = (t >= off) ? s[t - off] : 0;
        __syncthreads();
        s[t] += x;
        __syncthreads();
    }
    if (idx < NNODES) {
        int excl = s[t] - v + blockOffs[blockIdx.x];
        row_ptr[idx] = excl;
        if (idx == NNODES - 1) row_ptr[NNODES] = excl + v;
    }
}

// One wave per node; padded edge list (deg<=CAP always); register softmax;
// bf16 row gathers via 8-lane groups (uint4 = full row).
template <bool STORE_ATT, bool COMPUTE_Z, bool WRITE_F32, bool STORE_LA, bool COMPACT>
__global__ __launch_bounds__(256) void k_layer(const u16* __restrict__ hbf_in,
                                               const float* __restrict__ emb,
                                               const int* __restrict__ deg,
                                               const int* __restrict__ row_ptr,
                                               const u16* __restrict__ padded,
                                               const float* __restrict__ zs,
                                               const float* __restrict__ zd,
                                               float* __restrict__ att_csr,
                                               u16* __restrict__ csr_c,
                                               u16* __restrict__ dmap_c,
                                               float* __restrict__ h_out,
                                               u16* __restrict__ hbf_out,
                                               const float* __restrict__ ws,
                                               const float* __restrict__ wd,
                                               float* __restrict__ zs_out,
                                               float* __restrict__ zd_out,
                                               float* __restrict__ la) {
    int wid = (blockIdx.x * blockDim.x + threadIdx.x) >> 6;
    int lane = threadIdx.x & 63;
    if (wid >= NNODES) return;
    int ne = min(deg[wid], CAP);
    int s0 = 0;
    if (STORE_ATT || COMPACT) s0 = row_ptr[wid];
    float zdn = zd[wid];
    const int sub8 = lane >> 3, q8 = lane & 7;
    float acc[8];
    #pragma unroll
    for (int i = 0; i < 8; ++i) acc[i] = 0.f;

    int s = 0; float e = -INFINITY;
    bool valid = lane < ne;
    if (valid) {
        s = padded[(size_t)wid * CAP + lane];
        float z = zs[s] + zdn;
        e = z > 0.f ? z : GAMMA * z;
    }
    float m = wave_max(e);
    float ex = valid ? __expf(e - m) : 0.f;
    float dsum = wave_sum(ex);
    float inv = 1.f / fmaxf(dsum, 1e-16f);
    if (STORE_ATT && valid) att_csr[s0 + lane] = ex * inv;
    if (COMPACT && valid) {
        csr_c[s0 + lane] = (u16)s;
        dmap_c[s0 + lane] = (u16)wid;
    }
    for (int j = 0; j < ne; j += 16) {
        int ja = j + sub8, jb = j + 8 + sub8;
        float wa = __shfl(ex, ja, 64);
        float wb = __shfl(ex, jb, 64);
        int ta = __shfl(s, ja, 64);
        int tb = __shfl(s, jb, 64);
        const uint4 ra = *(const uint4*)&hbf_in[(size_t)ta * HDIM + 8 * q8];
        const uint4 rb = *(const uint4*)&hbf_in[(size_t)tb * HDIM + 8 * q8];
        acc[0] += wa * bflo(ra.x) + wb * bflo(rb.x);
        acc[1] += wa * bfhi(ra.x) + wb * bfhi(rb.x);
        acc[2] += wa * bflo(ra.y) + wb * bflo(rb.y);
        acc[3] += wa * bfhi(ra.y) + wb * bfhi(rb.y);
        acc[4] += wa * bflo(ra.z) + wb * bflo(rb.z);
        acc[5] += wa * bfhi(ra.z) + wb * bfhi(rb.z);
        acc[6] += wa * bflo(ra.w) + wb * bflo(rb.w);
        acc[7] += wa * bfhi(ra.w) + wb * bfhi(rb.w);
    }
    #pragma unroll
    for (int off = 8; off <= 32; off <<= 1) {
        #pragma unroll
        for (int i = 0; i < 8; ++i) acc[i] += __shfl_xor(acc[i], off, 64);
    }
    float hv[8];
    #pragma unroll
    for (int i = 0; i < 8; ++i) hv[i] = 0.f;
    float lap = 0.f;
    if (sub8 == 0) {
        const float4 e0 = *(const float4*)&emb[(size_t)wid * HDIM + 8 * q8];
        const float4 e1 = *(const float4*)&emb[(size_t)wid * HDIM + 8 * q8 + 4];
        hv[0] = 0.5f * (e0.x + acc[0] * inv);
        hv[1] = 0.5f * (e0.y + acc[1] * inv);
        hv[2] = 0.5f * (e0.z + acc[2] * inv);
        hv[3] = 0.5f * (e0.w + acc[3] * inv);
        hv[4] = 0.5f * (e1.x + acc[4] * inv);
        hv[5] = 0.5f * (e1.y + acc[5] * inv);
        hv[6] = 0.5f * (e1.z + acc[6] * inv);
        hv[7] = 0.5f * (e1.w + acc[7] * inv);
        if (WRITE_F32) {
            *(float4*)&h_out[(size_t)wid * HDIM + 8 * q8]     = make_float4(hv[0], hv[1], hv[2], hv[3]);
            *(float4*)&h_out[(size_t)wid * HDIM + 8 * q8 + 4] = make_float4(hv[4], hv[5], hv[6], hv[7]);
        }
        uint4 o;
        o.x = (u32)f2bf(hv[0]) | ((u32)f2bf(hv[1]) << 16);
        o.y = (u32)f2bf(hv[2]) | ((u32)f2bf(hv[3]) << 16);
        o.z = (u32)f2bf(hv[4]) | ((u32)f2bf(hv[5]) << 16);
        o.w = (u32)f2bf(hv[6]) | ((u32)f2bf(hv[7]) << 16);
        *(uint4*)&hbf_out[(size_t)wid * HDIM + 8 * q8] = o;
        if (STORE_LA) {
            float d0 = hv[0] - e0.x, d1 = hv[1] - e0.y, d2 = hv[2] - e0.z, d3 = hv[3] - e0.w;
            float d4 = hv[4] - e1.x, d5 = hv[5] - e1.y, d6 = hv[6] - e1.z, d7 = hv[7] - e1.w;
            lap = d0 * d0 + d1 * d1 + d2 * d2 + d3 * d3 +
                  d4 * d4 + d5 * d5 + d6 * d6 + d7 * d7;
        }
    }
    if (STORE_LA) {
        float lsum = wave_sum(lap);
        if (lane == 0) la[wid] = lsum;
    }
    if (COMPUTE_Z) {
        float pa = 0.f, pb = 0.f;
        if (sub8 == 0) {
            const float4 w0 = *(const float4*)&ws[8 * q8];
            const float4 w1 = *(const float4*)&ws[8 * q8 + 4];
            const float4 d0 = *(const float4*)&wd[8 * q8];
            const float4 d1 = *(const float4*)&wd[8 * q8 + 4];
            pa = hv[0] * w0.x + hv[1] * w0.y + hv[2] * w0.z + hv[3] * w0.w +
                 hv[4] * w1.x + hv[5] * w1.y + hv[6] * w1.z + hv[7] * w1.w;
            pb = hv[0] * d0.x + hv[1] * d0.y + hv[2] * d0.z + hv[3] * d0.w +
                 hv[4] * d1.x + hv[5] * d1.y + hv[6] * d1.z + hv[7] * d1.w;
        }
        float a = wave_sum(pa);
        float b = wave_sum(pb);
        if (lane == 0) { zs_out[wid] = a; zd_out[wid] = b; }
    }
}

// Loss: coalesced la sum (loss_a, precomputed by layer2) + edge-parallel loss_b
// over bf16 rows. One atomic per block.
__global__ __launch_bounds__(256) void k_loss(const float* __restrict__ la,
                                              const u16* __restrict__ hbf,
                                              const u16* __restrict__ csr_src,
                                              const u16* __restrict__ dst_map,
                                              const float* __restrict__ att_csr,
                                              float* __restrict__ acc) {
    const int lane = threadIdx.x & 63;
    const int wib = threadIdx.x >> 6;
    const int gtid = blockIdx.x * blockDim.x + threadIdx.x;
    const int nthreads = gridDim.x * blockDim.x;
    const int gw = gtid >> 6;
    const int nwaves = nthreads >> 6;
    const int sub8 = lane >> 3, q8 = lane & 7;
    float lb = 0.f;

    for (int i = gtid; i < NNODES / 4; i += nthreads) {
        const float4 v = *(const float4*)&la[i * 4];
        lb += 0.5f * (v.x + v.y + v.z + v.w);
    }
    if ((NNODES & 3) != 0 && gtid < (NNODES & 3)) lb += 0.5f * la[(NNODES & ~3) + gtid];

    for (int g = gw; g < NEDGES / 16; g += nwaves) {
        int e0 = g * 16 + sub8;
        int e1 = e0 + 8;
        int s0i = csr_src[e0], d0i = dst_map[e0];
        int s1i = csr_src[e1], d1i = dst_map[e1];
        const uint4 rs0 = *(const uint4*)&hbf[(size_t)s0i * HDIM + 8 * q8];
        const uint4 rd0 = *(const uint4*)&hbf[(size_t)d0i * HDIM + 8 * q8];
        const uint4 rs1 = *(const uint4*)&hbf[(size_t)s1i * HDIM + 8 * q8];
        const uint4 rd1 = *(const uint4*)&hbf[(size_t)d1i * HDIM + 8 * q8];
        float a0 = bflo(rd0.x) - bflo(rs0.x), a1 = bfhi(rd0.x) - bfhi(rs0.x);
        float a2 = bflo(rd0.y) - bflo(rs0.y), a3 = bfhi(rd0.y) - bfhi(rs0.y);
        float a4 = bflo(rd0.z) - bflo(rs0.z), a5 = bfhi(rd0.z) - bfhi(rs0.z);
        float a6 = bflo(rd0.w) - bflo(rs0.w), a7 = bfhi(rd0.w) - bfhi(rs0.w);
        float b0 = bflo(rd1.x) - bflo(rs1.x), b1 = bfhi(rd1.x) - bfhi(rs1.x);
        float b2 = bflo(rd1.y) - bflo(rs1.y), b3 = bfhi(rd1.y) - bfhi(rs1.y);
        float b4 = bflo(rd1.z) - bflo(rs1.z), b5 = bfhi(rd1.z) - bfhi(rs1.z);
        float b6 = bflo(rd1.w) - bflo(rs1.w), b7 = bfhi(rd1.w) - bfhi(rs1.w);
        float ss0 = group8_sum(a0 * a0 + a1 * a1 + a2 * a2 + a3 * a3 +
                               a4 * a4 + a5 * a5 + a6 * a6 + a7 * a7);
        float ss1 = group8_sum(b0 * b0 + b1 * b1 + b2 * b2 + b3 * b3 +
                               b4 * b4 + b5 * b5 + b6 * b6 + b7 * b7);
        if (q8 == 0)
            lb += 0.5f * (att_csr[e0] * sqrtf(ss0 + 1e-12f) +
                          att_csr[e1] * sqrtf(ss1 + 1e-12f));
    }
    lb = wave_sum(lb);
    __shared__ float part[4];
    if (lane == 0) part[wib] = lb;
    __syncthreads();
    if (threadIdx.x == 0)
        atomicAdd(acc, part[0] + part[1] + part[2] + part[3]);
}

__global__ void k_finalize(const float* __restrict__ acc, float* __restrict__ out_loss) {
    out_loss[0] = acc[0] / (float)NNODES;
}

extern "C" void kernel_launch(void* const* d_in, const int* in_sizes, int n_in,
                              void* d_out, int out_size, void* d_ws, size_t ws_size,
                              hipStream_t stream) {
    const float* emb  = (const float*)d_in[0];
    const float* Wfc  = (const float*)d_in[1];
    const float* attn = (const float*)d_in[2];
    const int*   src  = (const int*)d_in[3];
    const int*   dst  = (const int*)d_in[4];
    float* out = (float*)d_out; // [N*H] h, then [1] loss

    char* p = (char*)d_ws;
    int*   cursor  = (int*)p;   p += (size_t)NNODES * 4;   // deg after scatter
    float* lossAcc = (float*)p; p += 256;                   // zeroed with cursor
    int*   row_ptr = (int*)p;   p += (size_t)(NNODES + 1) * 4;
    int*   bsums   = (int*)p;   p += (size_t)SCAN_NB * 4;
    int*   boffs   = (int*)p;   p += (size_t)SCAN_NB * 4;
    int*   bcnt    = (int*)p;   p += (size_t)NWAVES_B1 * NPART * 4;
    float* wsv     = (float*)p; p += 64 * 4;
    float* wdv     = (float*)p; p += 64 * 4;
    float* zs0     = (float*)p; p += (size_t)NNODES * 4;
    float* zd0     = (float*)p; p += (size_t)NNODES * 4;
    float* zs1     = (float*)p; p += (size_t)NNODES * 4;
    float* zd1     = (float*)p; p += (size_t)NNODES * 4;
    float* laArr   = (float*)p; p += (size_t)NNODES * 4;
    float* att_csr = (float*)p; p += (size_t)NEDGES * 4;
    p = (char*)(((size_t)p + 255) & ~(size_t)255);
    u32*   region  = (u32*)p;   p += (size_t)NWAVES_B1 * NPART * BCAP * 4;
    u16*   padded  = (u16*)p;   p += (size_t)NNODES * CAP * 2;
    u16*   csr_src = (u16*)p;   p += (size_t)NEDGES * 2;
    u16*   dst_map = (u16*)p;   p += (size_t)NEDGES * 2;
    u16*   emb_bf  = (u16*)p;   p += (size_t)NNODES * HDIM * 2;
    u16*   h1_bf   = (u16*)p;   p += (size_t)NNODES * HDIM * 2;
    u16*   out_bf  = (u16*)p;   p += (size_t)NNODES * HDIM * 2;

    hipMemsetAsync(cursor, 0, (size_t)NNODES * 4 + 256, stream);  // cursor + lossAcc

    const int NB = (NNODES + 3) / 4;   // 12500 blocks, 1 node/wave

    k_wswd<<<1, 128, 0, stream>>>(Wfc, attn, wsv, wdv);
    k_bucket<<<NWAVES_B1 / 4, 256, 0, stream>>>((const int4*)src, (const int4*)dst,
                                                region, bcnt);
    k_scatter<<<NPART * 64, 256, 0, stream>>>(region, bcnt, cursor, padded);
    k_scan1z<<<NB, 256, 0, stream>>>(cursor, bsums, emb, wsv, wdv, emb_bf, zs0, zd0);
    k_scan2<<<1, SCAN_B, 0, stream>>>(bsums, boffs);
    k_scan3<<<SCAN_NB, SCAN_B, 0, stream>>>(cursor, boffs, row_ptr);

    // layer 1: gather emb_bf -> h1_bf, zs1/zd1; compact csr_src/dst_map
    k_layer<false, true, false, false, true><<<NB, 256, 0, stream>>>(
        emb_bf, emb, cursor, row_ptr, padded, zs0, zd0,
        att_csr, csr_src, dst_map, out /*unused*/, h1_bf, wsv, wdv, zs1, zd1, laArr);
    // layer 2: gather h1_bf -> out fp32 + out_bf; att; per-node loss_a
    k_layer<true, false, true, true, false><<<NB, 256, 0, stream>>>(
        h1_bf, emb, cursor, row_ptr, padded, zs1, zd1,
        att_csr, csr_src, dst_map, out, out_bf, wsv, wdv, zs0, zd0, laArr);

    k_loss<<<LOSS_GRID, 256, 0, stream>>>(laArr, out_bf, csr_src, dst_map, att_csr, lossAcc);
    k_finalize<<<1, 1, 0, stream>>>(lossAcc, out + (size_t)NNODES * HDIM);
}

// Round 13
// 228.813 us; speedup vs baseline: 1.0947x; 1.0947x over previous
//
#include <hip/hip_runtime.h>

#define NNODES 50000
#define NEDGES 800000
#define HDIM 64
#define CAP 64
#define GAMMA 0.2f
#define SCAN_B 256
#define SCAN_NB ((NNODES + SCAN_B - 1) / SCAN_B)   // 196
#define LOSS_GRID 2048
#define NPART 8
#define NODES_PER_PART ((NNODES + NPART - 1) / NPART)   // 6250
#define FILL_SLICES 192
#define E4 (NEDGES / 4)                                  // 200000 int4 chunks
#define CHUNK ((E4 + FILL_SLICES - 1) / FILL_SLICES)     // 1042

typedef unsigned short u16;
typedef unsigned int u32;

__device__ __forceinline__ u16 f2bf(float f) {
    u32 u = __float_as_uint(f);
    u32 r = (u + 0x7FFFu + ((u >> 16) & 1u)) >> 16;   // round-to-nearest-even
    return (u16)r;
}
__device__ __forceinline__ float bflo(u32 u) { return __uint_as_float(u << 16); }
__device__ __forceinline__ float bfhi(u32 u) { return __uint_as_float(u & 0xFFFF0000u); }

__device__ __forceinline__ float wave_sum(float v) {
    #pragma unroll
    for (int off = 32; off; off >>= 1) v += __shfl_xor(v, off, 64);
    return v;
}
__device__ __forceinline__ float wave_max(float v) {
    #pragma unroll
    for (int off = 32; off; off >>= 1) v = fmaxf(v, __shfl_xor(v, off, 64));
    return v;
}
__device__ __forceinline__ int wave_sum_i(int v) {
    #pragma unroll
    for (int off = 32; off; off >>= 1) v += __shfl_xor(v, off, 64);
    return v;
}
__device__ __forceinline__ float group8_sum(float v) {
    v += __shfl_xor(v, 1, 64);
    v += __shfl_xor(v, 2, 64);
    v += __shfl_xor(v, 4, 64);
    return v;
}

// Fused init: zero cursor (all blocks) + lossAcc; last block computes ws/wd.
__global__ __launch_bounds__(256) void k_init(int* __restrict__ cursor,
                                              float* __restrict__ lossAcc,
                                              const float* __restrict__ Wfc,
                                              const float* __restrict__ attn,
                                              float* __restrict__ ws, float* __restrict__ wd) {
    int t = threadIdx.x;
    int idx = blockIdx.x * 256 + t;
    if (idx < NNODES) cursor[idx] = 0;
    if (blockIdx.x == gridDim.x - 1) {
        if (t >= 80 && t < 96) lossAcc[t - 80] = 0.f;
        if (t >= 128) {
            int tt = t - 128;
            int k = tt & 63;
            const float* av = attn + ((tt >= 64) ? HDIM : 0);
            float s = 0.f;
            for (int j = 0; j < HDIM; ++j) s += Wfc[j * HDIM + k] * av[j];
            if (tt < 64) ws[k] = s; else wd[k] = s;
        }
    }
}

// Fused: XCD-partitioned padded CSR fill (single atomic pass; partition =
// blockIdx&7 so each node range's cursor/padded lines stay in one XCD L2)
// + zinit (emb_bf, zs0/zd0) across the full grid.
__global__ __launch_bounds__(256) void k_fillx(const int4* __restrict__ src4,
                                               const int4* __restrict__ dst4,
                                               int* __restrict__ cursor,
                                               u16* __restrict__ padded,
                                               const float* __restrict__ emb,
                                               const float* __restrict__ ws,
                                               const float* __restrict__ wd,
                                               u16* __restrict__ emb_bf,
                                               float* __restrict__ zs, float* __restrict__ zd) {
    // --- edge part: first NPART*FILL_SLICES blocks ---
    if (blockIdx.x < NPART * FILL_SLICES) {
        const int part = blockIdx.x & (NPART - 1);
        const int slice = blockIdx.x >> 3;
        const int lo = slice * CHUNK;
        const int hi = min(lo + CHUNK, E4);
        const int plo = part * NODES_PER_PART;
        const int phi = plo + NODES_PER_PART;
        for (int i = lo + threadIdx.x; i < hi; i += 256) {
            int4 s = src4[i];
            int4 d = dst4[i];
            if (d.x >= plo && d.x < phi) { int p0 = atomicAdd(&cursor[d.x], 1); if (p0 < CAP) padded[d.x * CAP + p0] = (u16)s.x; }
            if (d.y >= plo && d.y < phi) { int p1 = atomicAdd(&cursor[d.y], 1); if (p1 < CAP) padded[d.y * CAP + p1] = (u16)s.y; }
            if (d.z >= plo && d.z < phi) { int p2 = atomicAdd(&cursor[d.z], 1); if (p2 < CAP) padded[d.z * CAP + p2] = (u16)s.z; }
            if (d.w >= plo && d.w < phi) { int p3 = atomicAdd(&cursor[d.w], 1); if (p3 < CAP) padded[d.w * CAP + p3] = (u16)s.w; }
        }
    }
    // --- zinit part: one wave per node across the whole grid ---
    int tid = blockIdx.x * blockDim.x + threadIdx.x;
    int wid = tid >> 6;
    int lane = tid & 63;
    if (wid < NNODES) {
        float v = emb[wid * HDIM + lane];
        emb_bf[wid * HDIM + lane] = f2bf(v);
        float a = wave_sum(v * ws[lane]);
        float b = wave_sum(v * wd[lane]);
        if (lane == 0) { zs[wid] = a; zd[wid] = b; }
    }
}

// --- hierarchical scan of deg(=cursor, clamped) -> row_ptr (exclusive) ---
__global__ __launch_bounds__(SCAN_B) void k_scan1(const int* __restrict__ deg,
                                                  int* __restrict__ blockSums) {
    int t = threadIdx.x;
    int idx = blockIdx.x * SCAN_B + t;
    int v = (idx < NNODES) ? min(deg[idx], CAP) : 0;
    int ws = wave_sum_i(v);
    __shared__ int part[4];
    if ((t & 63) == 0) part[t >> 6] = ws;
    __syncthreads();
    if (t == 0) blockSums[blockIdx.x] = part[0] + part[1] + part[2] + part[3];
}

__global__ __launch_bounds__(SCAN_B) void k_scan2(int* __restrict__ blockSums,
                                                  int* __restrict__ blockOffs) {
    __shared__ int s[SCAN_B];
    int t = threadIdx.x;
    int v = (t < SCAN_NB) ? blockSums[t] : 0;
    s[t] = v;
    __syncthreads();
    for (int off = 1; off < SCAN_B; off <<= 1) {
        int x = (t >= off) ? s[t - off] : 0;
        __syncthreads();
        s[t] += x;
        __syncthreads();
    }
    if (t < SCAN_NB) blockOffs[t] = s[t] - v;   // exclusive
}

__global__ __launch_bounds__(SCAN_B) void k_scan3(const int* __restrict__ deg,
                                                  const int* __restrict__ blockOffs,
                                                  int* __restrict__ row_ptr) {
    __shared__ int s[SCAN_B];
    int t = threadIdx.x;
    int idx = blockIdx.x * SCAN_B + t;
    int v = (idx < NNODES) ? min(deg[idx], CAP) : 0;
    s[t] = v;
    __syncthreads();
    for (int off = 1; off < SCAN_B; off <<= 1) {
        int x = (t >= off) ? s[t - off] : 0;
        __syncthreads();
        s[t] += x;
        __syncthreads();
    }
    if (idx < NNODES) {
        int excl = s[t] - v + blockOffs[blockIdx.x];
        row_ptr[idx] = excl;
        if (idx == NNODES - 1) row_ptr[NNODES] = excl + v;
    }
}

// One wave per node; padded edge list (deg<=CAP always); register softmax;
// bf16 row gathers via 8-lane groups (uint4 = full row).
template <bool STORE_ATT, bool COMPUTE_Z, bool WRITE_F32, bool STORE_LA, bool COMPACT>
__global__ __launch_bounds__(256) void k_layer(const u16* __restrict__ hbf_in,
                                               const float* __restrict__ emb,
                                               const int* __restrict__ deg,
                                               const int* __restrict__ row_ptr,
                                               const u16* __restrict__ padded,
                                               const float* __restrict__ zs,
                                               const float* __restrict__ zd,
                                               float* __restrict__ att_csr,
                                               u16* __restrict__ csr_c,
                                               u16* __restrict__ dmap_c,
                                               float* __restrict__ h_out,
                                               u16* __restrict__ hbf_out,
                                               const float* __restrict__ ws,
                                               const float* __restrict__ wd,
                                               float* __restrict__ zs_out,
                                               float* __restrict__ zd_out,
                                               float* __restrict__ la) {
    int wid = (blockIdx.x * blockDim.x + threadIdx.x) >> 6;
    int lane = threadIdx.x & 63;
    if (wid >= NNODES) return;
    int ne = min(deg[wid], CAP);
    int s0 = 0;
    if (STORE_ATT || COMPACT) s0 = row_ptr[wid];
    float zdn = zd[wid];
    const int sub8 = lane >> 3, q8 = lane & 7;
    float acc[8];
    #pragma unroll
    for (int i = 0; i < 8; ++i) acc[i] = 0.f;

    int s = 0; float e = -INFINITY;
    bool valid = lane < ne;
    if (valid) {
        s = padded[(size_t)wid * CAP + lane];
        float z = zs[s] + zdn;
        e = z > 0.f ? z : GAMMA * z;
    }
    float m = wave_max(e);
    float ex = valid ? __expf(e - m) : 0.f;
    float dsum = wave_sum(ex);
    float inv = 1.f / fmaxf(dsum, 1e-16f);
    if (STORE_ATT && valid) att_csr[s0 + lane] = ex * inv;
    if (COMPACT && valid) {
        csr_c[s0 + lane] = (u16)s;
        dmap_c[s0 + lane] = (u16)wid;
    }
    for (int j = 0; j < ne; j += 16) {
        int ja = j + sub8, jb = j + 8 + sub8;
        float wa = __shfl(ex, ja, 64);
        float wb = __shfl(ex, jb, 64);
        int ta = __shfl(s, ja, 64);
        int tb = __shfl(s, jb, 64);
        const uint4 ra = *(const uint4*)&hbf_in[(size_t)ta * HDIM + 8 * q8];
        const uint4 rb = *(const uint4*)&hbf_in[(size_t)tb * HDIM + 8 * q8];
        acc[0] += wa * bflo(ra.x) + wb * bflo(rb.x);
        acc[1] += wa * bfhi(ra.x) + wb * bfhi(rb.x);
        acc[2] += wa * bflo(ra.y) + wb * bflo(rb.y);
        acc[3] += wa * bfhi(ra.y) + wb * bfhi(rb.y);
        acc[4] += wa * bflo(ra.z) + wb * bflo(rb.z);
        acc[5] += wa * bfhi(ra.z) + wb * bfhi(rb.z);
        acc[6] += wa * bflo(ra.w) + wb * bflo(rb.w);
        acc[7] += wa * bfhi(ra.w) + wb * bfhi(rb.w);
    }
    #pragma unroll
    for (int off = 8; off <= 32; off <<= 1) {
        #pragma unroll
        for (int i = 0; i < 8; ++i) acc[i] += __shfl_xor(acc[i], off, 64);
    }
    float hv[8];
    #pragma unroll
    for (int i = 0; i < 8; ++i) hv[i] = 0.f;
    float lap = 0.f;
    if (sub8 == 0) {
        const float4 e0 = *(const float4*)&emb[(size_t)wid * HDIM + 8 * q8];
        const float4 e1 = *(const float4*)&emb[(size_t)wid * HDIM + 8 * q8 + 4];
        hv[0] = 0.5f * (e0.x + acc[0] * inv);
        hv[1] = 0.5f * (e0.y + acc[1] * inv);
        hv[2] = 0.5f * (e0.z + acc[2] * inv);
        hv[3] = 0.5f * (e0.w + acc[3] * inv);
        hv[4] = 0.5f * (e1.x + acc[4] * inv);
        hv[5] = 0.5f * (e1.y + acc[5] * inv);
        hv[6] = 0.5f * (e1.z + acc[6] * inv);
        hv[7] = 0.5f * (e1.w + acc[7] * inv);
        if (WRITE_F32) {
            *(float4*)&h_out[(size_t)wid * HDIM + 8 * q8]     = make_float4(hv[0], hv[1], hv[2], hv[3]);
            *(float4*)&h_out[(size_t)wid * HDIM + 8 * q8 + 4] = make_float4(hv[4], hv[5], hv[6], hv[7]);
        }
        uint4 o;
        o.x = (u32)f2bf(hv[0]) | ((u32)f2bf(hv[1]) << 16);
        o.y = (u32)f2bf(hv[2]) | ((u32)f2bf(hv[3]) << 16);
        o.z = (u32)f2bf(hv[4]) | ((u32)f2bf(hv[5]) << 16);
        o.w = (u32)f2bf(hv[6]) | ((u32)f2bf(hv[7]) << 16);
        *(uint4*)&hbf_out[(size_t)wid * HDIM + 8 * q8] = o;
        if (STORE_LA) {
            float d0 = hv[0] - e0.x, d1 = hv[1] - e0.y, d2 = hv[2] - e0.z, d3 = hv[3] - e0.w;
            float d4 = hv[4] - e1.x, d5 = hv[5] - e1.y, d6 = hv[6] - e1.z, d7 = hv[7] - e1.w;
            lap = d0 * d0 + d1 * d1 + d2 * d2 + d3 * d3 +
                  d4 * d4 + d5 * d5 + d6 * d6 + d7 * d7;
        }
    }
    if (STORE_LA) {
        float lsum = wave_sum(lap);
        if (lane == 0) la[wid] = lsum;
    }
    if (COMPUTE_Z) {
        float pa = 0.f, pb = 0.f;
        if (sub8 == 0) {
            const float4 w0 = *(const float4*)&ws[8 * q8];
            const float4 w1 = *(const float4*)&ws[8 * q8 + 4];
            const float4 d0 = *(const float4*)&wd[8 * q8];
            const float4 d1 = *(const float4*)&wd[8 * q8 + 4];
            pa = hv[0] * w0.x + hv[1] * w0.y + hv[2] * w0.z + hv[3] * w0.w +
                 hv[4] * w1.x + hv[5] * w1.y + hv[6] * w1.z + hv[7] * w1.w;
            pb = hv[0] * d0.x + hv[1] * d0.y + hv[2] * d0.z + hv[3] * d0.w +
                 hv[4] * d1.x + hv[5] * d1.y + hv[6] * d1.z + hv[7] * d1.w;
        }
        float a = wave_sum(pa);
        float b = wave_sum(pb);
        if (lane == 0) { zs_out[wid] = a; zd_out[wid] = b; }
    }
}

// Loss: coalesced la sum (loss_a, precomputed by layer2) + edge-parallel loss_b
// over bf16 rows, 32 edges/wave/iter (4 per 8-lane group, 8 gathers in flight).
__global__ __launch_bounds__(256) void k_loss(const float* __restrict__ la,
                                              const u16* __restrict__ hbf,
                                              const u16* __restrict__ csr_src,
                                              const u16* __restrict__ dst_map,
                                              const float* __restrict__ att_csr,
                                              float* __restrict__ acc) {
    const int lane = threadIdx.x & 63;
    const int wib = threadIdx.x >> 6;
    const int gtid = blockIdx.x * blockDim.x + threadIdx.x;
    const int nthreads = gridDim.x * blockDim.x;
    const int gw = gtid >> 6;
    const int nwaves = nthreads >> 6;
    const int sub8 = lane >> 3, q8 = lane & 7;
    float lb = 0.f;

    for (int i = gtid; i < NNODES / 4; i += nthreads) {
        const float4 v = *(const float4*)&la[i * 4];
        lb += 0.5f * (v.x + v.y + v.z + v.w);
    }
    if ((NNODES & 3) != 0 && gtid < (NNODES & 3)) lb += 0.5f * la[(NNODES & ~3) + gtid];

    for (int g = gw; g < NEDGES / 32; g += nwaves) {
        int e0 = g * 32 + sub8;
        int e1 = e0 + 8, e2 = e0 + 16, e3 = e0 + 24;
        int s0i = csr_src[e0], d0i = dst_map[e0];
        int s1i = csr_src[e1], d1i = dst_map[e1];
        int s2i = csr_src[e2], d2i = dst_map[e2];
        int s3i = csr_src[e3], d3i = dst_map[e3];
        const uint4 rs0 = *(const uint4*)&hbf[(size_t)s0i * HDIM + 8 * q8];
        const uint4 rd0 = *(const uint4*)&hbf[(size_t)d0i * HDIM + 8 * q8];
        const uint4 rs1 = *(const uint4*)&hbf[(size_t)s1i * HDIM + 8 * q8];
        const uint4 rd1 = *(const uint4*)&hbf[(size_t)d1i * HDIM + 8 * q8];
        const uint4 rs2 = *(const uint4*)&hbf[(size_t)s2i * HDIM + 8 * q8];
        const uint4 rd2 = *(const uint4*)&hbf[(size_t)d2i * HDIM + 8 * q8];
        const uint4 rs3 = *(const uint4*)&hbf[(size_t)s3i * HDIM + 8 * q8];
        const uint4 rd3 = *(const uint4*)&hbf[(size_t)d3i * HDIM + 8 * q8];
        float a0 = bflo(rd0.x) - bflo(rs0.x), a1 = bfhi(rd0.x) - bfhi(rs0.x);
        float a2 = bflo(rd0.y) - bflo(rs0.y), a3 = bfhi(rd0.y) - bfhi(rs0.y);
        float a4 = bflo(rd0.z) - bflo(rs0.z), a5 = bfhi(rd0.z) - bfhi(rs0.z);
        float a6 = bflo(rd0.w) - bflo(rs0.w), a7 = bfhi(rd0.w) - bfhi(rs0.w);
        float b0 = bflo(rd1.x) - bflo(rs1.x), b1 = bfhi(rd1.x) - bfhi(rs1.x);
        float b2 = bflo(rd1.y) - bflo(rs1.y), b3 = bfhi(rd1.y) - bfhi(rs1.y);
        float b4 = bflo(rd1.z) - bflo(rs1.z), b5 = bfhi(rd1.z) - bfhi(rs1.z);
        float b6 = bflo(rd1.w) - bflo(rs1.w), b7 = bfhi(rd1.w) - bfhi(rs1.w);
        float c0 = bflo(rd2.x) - bflo(rs2.x), c1 = bfhi(rd2.x) - bfhi(rs2.x);
        float c2 = bflo(rd2.y) - bflo(rs2.y), c3 = bfhi(rd2.y) - bfhi(rs2.y);
        float c4 = bflo(rd2.z) - bflo(rs2.z), c5 = bfhi(rd2.z) - bfhi(rs2.z);
        float c6 = bflo(rd2.w) - bflo(rs2.w), c7 = bfhi(rd2.w) - bfhi(rs2.w);
        float g0 = bflo(rd3.x) - bflo(rs3.x), g1 = bfhi(rd3.x) - bfhi(rs3.x);
        float g2 = bflo(rd3.y) - bflo(rs3.y), g3 = bfhi(rd3.y) - bfhi(rs3.y);
        float g4 = bflo(rd3.z) - bflo(rs3.z), g5 = bfhi(rd3.z) - bfhi(rs3.z);
        float g6 = bflo(rd3.w) - bflo(rs3.w), g7 = bfhi(rd3.w) - bfhi(rs3.w);
        float ss0 = group8_sum(a0 * a0 + a1 * a1 + a2 * a2 + a3 * a3 +
                               a4 * a4 + a5 * a5 + a6 * a6 + a7 * a7);
        float ss1 = group8_sum(b0 * b0 + b1 * b1 + b2 * b2 + b3 * b3 +
                               b4 * b4 + b5 * b5 + b6 * b6 + b7 * b7);
        float ss2 = group8_sum(c0 * c0 + c1 * c1 + c2 * c2 + c3 * c3 +
                               c4 * c4 + c5 * c5 + c6 * c6 + c7 * c7);
        float ss3 = group8_sum(g0 * g0 + g1 * g1 + g2 * g2 + g3 * g3 +
                               g4 * g4 + g5 * g5 + g6 * g6 + g7 * g7);
        if (q8 == 0)
            lb += 0.5f * (att_csr[e0] * sqrtf(ss0 + 1e-12f) +
                          att_csr[e1] * sqrtf(ss1 + 1e-12f) +
                          att_csr[e2] * sqrtf(ss2 + 1e-12f) +
                          att_csr[e3] * sqrtf(ss3 + 1e-12f));
    }
    lb = wave_sum(lb);
    __shared__ float part[4];
    if (lane == 0) part[wib] = lb;
    __syncthreads();
    if (threadIdx.x == 0)
        atomicAdd(acc, part[0] + part[1] + part[2] + part[3]);
}

__global__ void k_finalize(const float* __restrict__ acc, float* __restrict__ out_loss) {
    out_loss[0] = acc[0] / (float)NNODES;
}

extern "C" void kernel_launch(void* const* d_in, const int* in_sizes, int n_in,
                              void* d_out, int out_size, void* d_ws, size_t ws_size,
                              hipStream_t stream) {
    const float* emb  = (const float*)d_in[0];
    const float* Wfc  = (const float*)d_in[1];
    const float* attn = (const float*)d_in[2];
    const int*   src  = (const int*)d_in[3];
    const int*   dst  = (const int*)d_in[4];
    float* out = (float*)d_out; // [N*H] h, then [1] loss

    char* p = (char*)d_ws;
    int*   cursor  = (int*)p;   p += (size_t)NNODES * 4;   // deg after fill
    float* lossAcc = (float*)p; p += 256;
    int*   row_ptr = (int*)p;   p += (size_t)(NNODES + 1) * 4;
    int*   bsums   = (int*)p;   p += (size_t)SCAN_NB * 4;
    int*   boffs   = (int*)p;   p += (size_t)SCAN_NB * 4;
    float* wsv     = (float*)p; p += 64 * 4;
    float* wdv     = (float*)p; p += 64 * 4;
    float* zs0     = (float*)p; p += (size_t)NNODES * 4;
    float* zd0     = (float*)p; p += (size_t)NNODES * 4;
    float* zs1     = (float*)p; p += (size_t)NNODES * 4;
    float* zd1     = (float*)p; p += (size_t)NNODES * 4;
    float* laArr   = (float*)p; p += (size_t)NNODES * 4;
    float* att_csr = (float*)p; p += (size_t)NEDGES * 4;
    p = (char*)(((size_t)p + 255) & ~(size_t)255);
    u16*   padded  = (u16*)p;   p += (size_t)NNODES * CAP * 2;
    u16*   csr_src = (u16*)p;   p += (size_t)NEDGES * 2;
    u16*   dst_map = (u16*)p;   p += (size_t)NEDGES * 2;
    u16*   emb_bf  = (u16*)p;   p += (size_t)NNODES * HDIM * 2;
    u16*   h1_bf   = (u16*)p;   p += (size_t)NNODES * HDIM * 2;
    u16*   out_bf  = (u16*)p;   p += (size_t)NNODES * HDIM * 2;

    const int NB = (NNODES + 3) / 4;   // 12500 blocks, 1 node/wave

    k_init<<<SCAN_NB, 256, 0, stream>>>(cursor, lossAcc, Wfc, attn, wsv, wdv);
    k_fillx<<<NB, 256, 0, stream>>>((const int4*)src, (const int4*)dst, cursor, padded,
                                    emb, wsv, wdv, emb_bf, zs0, zd0);
    k_scan1<<<SCAN_NB, SCAN_B, 0, stream>>>(cursor, bsums);
    k_scan2<<<1, SCAN_B, 0, stream>>>(bsums, boffs);
    k_scan3<<<SCAN_NB, SCAN_B, 0, stream>>>(cursor, boffs, row_ptr);

    // layer 1: gather emb_bf -> h1_bf, zs1/zd1; compact csr_src/dst_map
    k_layer<false, true, false, false, true><<<NB, 256, 0, stream>>>(
        emb_bf, emb, cursor, row_ptr, padded, zs0, zd0,
        att_csr, csr_src, dst_map, out /*unused*/, h1_bf, wsv, wdv, zs1, zd1, laArr);
    // layer 2: gather h1_bf -> out fp32 + out_bf; att; per-node loss_a
    k_layer<true, false, true, true, false><<<NB, 256, 0, stream>>>(
        h1_bf, emb, cursor, row_ptr, padded, zs1, zd1,
        att_csr, csr_src, dst_map, out, out_bf, wsv, wdv, zs0, zd0, laArr);

    k_loss<<<LOSS_GRID, 256, 0, stream>>>(laArr, out_bf, csr_src, dst_map, att_csr, lossAcc);
    k_finalize<<<1, 1, 0, stream>>>(lossAcc, out + (size_t)NNODES * HDIM);
}

// Round 14
// 227.624 us; speedup vs baseline: 1.1005x; 1.0052x over previous
//
#include <hip/hip_runtime.h>

#define NNODES 50000
#define NEDGES 800000
#define HDIM 64
#define CAP 64
#define GAMMA 0.2f
#define SCAN_B 256
#define SCAN_NB ((NNODES + SCAN_B - 1) / SCAN_B)   // 196
#define LOSS_GRID 2048
#define NPART 8
#define NODES_PER_PART ((NNODES + NPART - 1) / NPART)   // 6250
#define FILL_SLICES 192
#define E4 (NEDGES / 4)                                  // 200000 int4 chunks
#define CHUNK ((E4 + FILL_SLICES - 1) / FILL_SLICES)     // 1042

typedef unsigned short u16;
typedef unsigned int u32;

__device__ __forceinline__ u16 f2bf(float f) {
    u32 u = __float_as_uint(f);
    u32 r = (u + 0x7FFFu + ((u >> 16) & 1u)) >> 16;   // round-to-nearest-even
    return (u16)r;
}
__device__ __forceinline__ float bflo(u32 u) { return __uint_as_float(u << 16); }
__device__ __forceinline__ float bfhi(u32 u) { return __uint_as_float(u & 0xFFFF0000u); }

__device__ __forceinline__ float wave_sum(float v) {
    #pragma unroll
    for (int off = 32; off; off >>= 1) v += __shfl_xor(v, off, 64);
    return v;
}
__device__ __forceinline__ float wave_max(float v) {
    #pragma unroll
    for (int off = 32; off; off >>= 1) v = fmaxf(v, __shfl_xor(v, off, 64));
    return v;
}
__device__ __forceinline__ int wave_sum_i(int v) {
    #pragma unroll
    for (int off = 32; off; off >>= 1) v += __shfl_xor(v, off, 64);
    return v;
}
__device__ __forceinline__ float group8_sum(float v) {
    v += __shfl_xor(v, 1, 64);
    v += __shfl_xor(v, 2, 64);
    v += __shfl_xor(v, 4, 64);
    return v;
}

// Fused init: zero cursor (all blocks) + lossAcc; last block computes ws/wd.
__global__ __launch_bounds__(256) void k_init(int* __restrict__ cursor,
                                              float* __restrict__ lossAcc,
                                              const float* __restrict__ Wfc,
                                              const float* __restrict__ attn,
                                              float* __restrict__ ws, float* __restrict__ wd) {
    int t = threadIdx.x;
    int idx = blockIdx.x * 256 + t;
    if (idx < NNODES) cursor[idx] = 0;
    if (blockIdx.x == gridDim.x - 1) {
        if (t >= 80 && t < 96) lossAcc[t - 80] = 0.f;
        if (t >= 128) {
            int tt = t - 128;
            int k = tt & 63;
            const float* av = attn + ((tt >= 64) ? HDIM : 0);
            float s = 0.f;
            for (int j = 0; j < HDIM; ++j) s += Wfc[j * HDIM + k] * av[j];
            if (tt < 64) ws[k] = s; else wd[k] = s;
        }
    }
}

// PURE XCD-partitioned padded CSR fill (single atomic pass; partition =
// blockIdx&7 so each node range's cursor/padded lines stay in one XCD L2).
// src4 load skipped when no edge in the int4 belongs to this partition.
__global__ __launch_bounds__(256) void k_fillx(const int4* __restrict__ src4,
                                               const int4* __restrict__ dst4,
                                               int* __restrict__ cursor,
                                               u16* __restrict__ padded) {
    const int part = blockIdx.x & (NPART - 1);
    const int slice = blockIdx.x >> 3;
    const int lo = slice * CHUNK;
    const int hi = min(lo + CHUNK, E4);
    const int plo = part * NODES_PER_PART;
    const int phi = plo + NODES_PER_PART;
    for (int i = lo + threadIdx.x; i < hi; i += 256) {
        int4 d = dst4[i];
        bool mx = d.x >= plo && d.x < phi;
        bool my = d.y >= plo && d.y < phi;
        bool mz = d.z >= plo && d.z < phi;
        bool mw = d.w >= plo && d.w < phi;
        if (mx | my | mz | mw) {
            int4 s = src4[i];
            if (mx) { int p0 = atomicAdd(&cursor[d.x], 1); if (p0 < CAP) padded[d.x * CAP + p0] = (u16)s.x; }
            if (my) { int p1 = atomicAdd(&cursor[d.y], 1); if (p1 < CAP) padded[d.y * CAP + p1] = (u16)s.y; }
            if (mz) { int p2 = atomicAdd(&cursor[d.z], 1); if (p2 < CAP) padded[d.z * CAP + p2] = (u16)s.z; }
            if (mw) { int p3 = atomicAdd(&cursor[d.w], 1); if (p3 < CAP) padded[d.w * CAP + p3] = (u16)s.w; }
        }
    }
}

// scan phase 1 (first SCAN_NB blocks) + zinit (emb_bf, zs0/zd0) on the full grid
__global__ __launch_bounds__(256) void k_scan1z(const int* __restrict__ deg,
                                                int* __restrict__ blockSums,
                                                const float* __restrict__ emb,
                                                const float* __restrict__ ws,
                                                const float* __restrict__ wd,
                                                u16* __restrict__ emb_bf,
                                                float* __restrict__ zs, float* __restrict__ zd) {
    int t = threadIdx.x;
    if (blockIdx.x < SCAN_NB) {
        int idx = blockIdx.x * SCAN_B + t;
        int v = (idx < NNODES) ? min(deg[idx], CAP) : 0;
        int wsum = wave_sum_i(v);
        __shared__ int part[4];
        if ((t & 63) == 0) part[t >> 6] = wsum;
        __syncthreads();
        if (t == 0) blockSums[blockIdx.x] = part[0] + part[1] + part[2] + part[3];
    }
    int tid = blockIdx.x * blockDim.x + threadIdx.x;
    int wid = tid >> 6;
    int lane = tid & 63;
    if (wid < NNODES) {
        float v = emb[wid * HDIM + lane];
        emb_bf[wid * HDIM + lane] = f2bf(v);
        float a = wave_sum(v * ws[lane]);
        float b = wave_sum(v * wd[lane]);
        if (lane == 0) { zs[wid] = a; zd[wid] = b; }
    }
}

// scan3 with fused scan2: each block first scans the 196 block sums in LDS
// (redundantly), then does its per-element scan.
__global__ __launch_bounds__(SCAN_B) void k_scan3(const int* __restrict__ deg,
                                                  const int* __restrict__ blockSums,
                                                  int* __restrict__ row_ptr) {
    __shared__ int s[SCAN_B];
    int t = threadIdx.x;
    // phase A: inclusive scan of block sums
    int bv = (t < SCAN_NB) ? blockSums[t] : 0;
    s[t] = bv;
    __syncthreads();
    for (int off = 1; off < SCAN_B; off <<= 1) {
        int x = (t >= off) ? s[t - off] : 0;
        __syncthreads();
        s[t] += x;
        __syncthreads();
    }
    int blockOff = (blockIdx.x > 0) ? s[blockIdx.x - 1] : 0;
    __syncthreads();
    // phase B: per-element scan
    int idx = blockIdx.x * SCAN_B + t;
    int v = (idx < NNODES) ? min(deg[idx], CAP) : 0;
    s[t] = v;
    __syncthreads();
    for (int off = 1; off < SCAN_B; off <<= 1) {
        int x = (t >= off) ? s[t - off] : 0;
        __syncthreads();
        s[t] += x;
        __syncthreads();
    }
    if (idx < NNODES) {
        int excl = s[t] - v + blockOff;
        row_ptr[idx] = excl;
        if (idx == NNODES - 1) row_ptr[NNODES] = excl + v;
    }
}

// One wave per node; padded edge list (deg<=CAP always); register softmax;
// bf16 row gathers via 8-lane groups (uint4 = full row).
template <bool STORE_ATT, bool COMPUTE_Z, bool WRITE_F32, bool STORE_LA, bool COMPACT>
__global__ __launch_bounds__(256) void k_layer(const u16* __restrict__ hbf_in,
                                               const float* __restrict__ emb,
                                               const int* __restrict__ deg,
                                               const int* __restrict__ row_ptr,
                                               const u16* __restrict__ padded,
                                               const float* __restrict__ zs,
                                               const float* __restrict__ zd,
                                               float* __restrict__ att_csr,
                                               u16* __restrict__ csr_c,
                                               u16* __restrict__ dmap_c,
                                               float* __restrict__ h_out,
                                               u16* __restrict__ hbf_out,
                                               const float* __restrict__ ws,
                                               const float* __restrict__ wd,
                                               float* __restrict__ zs_out,
                                               float* __restrict__ zd_out,
                                               float* __restrict__ la) {
    int wid = (blockIdx.x * blockDim.x + threadIdx.x) >> 6;
    int lane = threadIdx.x & 63;
    if (wid >= NNODES) return;
    int ne = min(deg[wid], CAP);
    int s0 = 0;
    if (STORE_ATT || COMPACT) s0 = row_ptr[wid];
    float zdn = zd[wid];
    const int sub8 = lane >> 3, q8 = lane & 7;
    float acc[8];
    #pragma unroll
    for (int i = 0; i < 8; ++i) acc[i] = 0.f;

    int s = 0; float e = -INFINITY;
    bool valid = lane < ne;
    if (valid) {
        s = padded[(size_t)wid * CAP + lane];
        float z = zs[s] + zdn;
        e = z > 0.f ? z : GAMMA * z;
    }
    float m = wave_max(e);
    float ex = valid ? __expf(e - m) : 0.f;
    float dsum = wave_sum(ex);
    float inv = 1.f / fmaxf(dsum, 1e-16f);
    if (STORE_ATT && valid) att_csr[s0 + lane] = ex * inv;
    if (COMPACT && valid) {
        csr_c[s0 + lane] = (u16)s;
        dmap_c[s0 + lane] = (u16)wid;
    }
    for (int j = 0; j < ne; j += 16) {
        int ja = j + sub8, jb = j + 8 + sub8;
        float wa = __shfl(ex, ja, 64);
        float wb = __shfl(ex, jb, 64);
        int ta = __shfl(s, ja, 64);
        int tb = __shfl(s, jb, 64);
        const uint4 ra = *(const uint4*)&hbf_in[(size_t)ta * HDIM + 8 * q8];
        const uint4 rb = *(const uint4*)&hbf_in[(size_t)tb * HDIM + 8 * q8];
        acc[0] += wa * bflo(ra.x) + wb * bflo(rb.x);
        acc[1] += wa * bfhi(ra.x) + wb * bfhi(rb.x);
        acc[2] += wa * bflo(ra.y) + wb * bflo(rb.y);
        acc[3] += wa * bfhi(ra.y) + wb * bfhi(rb.y);
        acc[4] += wa * bflo(ra.z) + wb * bflo(rb.z);
        acc[5] += wa * bfhi(ra.z) + wb * bfhi(rb.z);
        acc[6] += wa * bflo(ra.w) + wb * bflo(rb.w);
        acc[7] += wa * bfhi(ra.w) + wb * bfhi(rb.w);
    }
    #pragma unroll
    for (int off = 8; off <= 32; off <<= 1) {
        #pragma unroll
        for (int i = 0; i < 8; ++i) acc[i] += __shfl_xor(acc[i], off, 64);
    }
    float hv[8];
    #pragma unroll
    for (int i = 0; i < 8; ++i) hv[i] = 0.f;
    float lap = 0.f;
    if (sub8 == 0) {
        const float4 e0 = *(const float4*)&emb[(size_t)wid * HDIM + 8 * q8];
        const float4 e1 = *(const float4*)&emb[(size_t)wid * HDIM + 8 * q8 + 4];
        hv[0] = 0.5f * (e0.x + acc[0] * inv);
        hv[1] = 0.5f * (e0.y + acc[1] * inv);
        hv[2] = 0.5f * (e0.z + acc[2] * inv);
        hv[3] = 0.5f * (e0.w + acc[3] * inv);
        hv[4] = 0.5f * (e1.x + acc[4] * inv);
        hv[5] = 0.5f * (e1.y + acc[5] * inv);
        hv[6] = 0.5f * (e1.z + acc[6] * inv);
        hv[7] = 0.5f * (e1.w + acc[7] * inv);
        if (WRITE_F32) {
            *(float4*)&h_out[(size_t)wid * HDIM + 8 * q8]     = make_float4(hv[0], hv[1], hv[2], hv[3]);
            *(float4*)&h_out[(size_t)wid * HDIM + 8 * q8 + 4] = make_float4(hv[4], hv[5], hv[6], hv[7]);
        }
        uint4 o;
        o.x = (u32)f2bf(hv[0]) | ((u32)f2bf(hv[1]) << 16);
        o.y = (u32)f2bf(hv[2]) | ((u32)f2bf(hv[3]) << 16);
        o.z = (u32)f2bf(hv[4]) | ((u32)f2bf(hv[5]) << 16);
        o.w = (u32)f2bf(hv[6]) | ((u32)f2bf(hv[7]) << 16);
        *(uint4*)&hbf_out[(size_t)wid * HDIM + 8 * q8] = o;
        if (STORE_LA) {
            float d0 = hv[0] - e0.x, d1 = hv[1] - e0.y, d2 = hv[2] - e0.z, d3 = hv[3] - e0.w;
            float d4 = hv[4] - e1.x, d5 = hv[5] - e1.y, d6 = hv[6] - e1.z, d7 = hv[7] - e1.w;
            lap = d0 * d0 + d1 * d1 + d2 * d2 + d3 * d3 +
                  d4 * d4 + d5 * d5 + d6 * d6 + d7 * d7;
        }
    }
    if (STORE_LA) {
        float lsum = wave_sum(lap);
        if (lane == 0) la[wid] = lsum;
    }
    if (COMPUTE_Z) {
        float pa = 0.f, pb = 0.f;
        if (sub8 == 0) {
            const float4 w0 = *(const float4*)&ws[8 * q8];
            const float4 w1 = *(const float4*)&ws[8 * q8 + 4];
            const float4 d0 = *(const float4*)&wd[8 * q8];
            const float4 d1 = *(const float4*)&wd[8 * q8 + 4];
            pa = hv[0] * w0.x + hv[1] * w0.y + hv[2] * w0.z + hv[3] * w0.w +
                 hv[4] * w1.x + hv[5] * w1.y + hv[6] * w1.z + hv[7] * w1.w;
            pb = hv[0] * d0.x + hv[1] * d0.y + hv[2] * d0.z + hv[3] * d0.w +
                 hv[4] * d1.x + hv[5] * d1.y + hv[6] * d1.z + hv[7] * d1.w;
        }
        float a = wave_sum(pa);
        float b = wave_sum(pb);
        if (lane == 0) { zs_out[wid] = a; zd_out[wid] = b; }
    }
}

// Loss: coalesced la sum (loss_a, precomputed by layer2) + edge-parallel loss_b
// over bf16 rows, 32 edges/wave/iter (4 per 8-lane group, 8 gathers in flight).
__global__ __launch_bounds__(256) void k_loss(const float* __restrict__ la,
                                              const u16* __restrict__ hbf,
                                              const u16* __restrict__ csr_src,
                                              const u16* __restrict__ dst_map,
                                              const float* __restrict__ att_csr,
                                              float* __restrict__ acc) {
    const int lane = threadIdx.x & 63;
    const int wib = threadIdx.x >> 6;
    const int gtid = blockIdx.x * blockDim.x + threadIdx.x;
    const int nthreads = gridDim.x * blockDim.x;
    const int gw = gtid >> 6;
    const int nwaves = nthreads >> 6;
    const int sub8 = lane >> 3, q8 = lane & 7;
    float lb = 0.f;

    for (int i = gtid; i < NNODES / 4; i += nthreads) {
        const float4 v = *(const float4*)&la[i * 4];
        lb += 0.5f * (v.x + v.y + v.z + v.w);
    }
    if ((NNODES & 3) != 0 && gtid < (NNODES & 3)) lb += 0.5f * la[(NNODES & ~3) + gtid];

    for (int g = gw; g < NEDGES / 32; g += nwaves) {
        int e0 = g * 32 + sub8;
        int e1 = e0 + 8, e2 = e0 + 16, e3 = e0 + 24;
        int s0i = csr_src[e0], d0i = dst_map[e0];
        int s1i = csr_src[e1], d1i = dst_map[e1];
        int s2i = csr_src[e2], d2i = dst_map[e2];
        int s3i = csr_src[e3], d3i = dst_map[e3];
        const uint4 rs0 = *(const uint4*)&hbf[(size_t)s0i * HDIM + 8 * q8];
        const uint4 rd0 = *(const uint4*)&hbf[(size_t)d0i * HDIM + 8 * q8];
        const uint4 rs1 = *(const uint4*)&hbf[(size_t)s1i * HDIM + 8 * q8];
        const uint4 rd1 = *(const uint4*)&hbf[(size_t)d1i * HDIM + 8 * q8];
        const uint4 rs2 = *(const uint4*)&hbf[(size_t)s2i * HDIM + 8 * q8];
        const uint4 rd2 = *(const uint4*)&hbf[(size_t)d2i * HDIM + 8 * q8];
        const uint4 rs3 = *(const uint4*)&hbf[(size_t)s3i * HDIM + 8 * q8];
        const uint4 rd3 = *(const uint4*)&hbf[(size_t)d3i * HDIM + 8 * q8];
        float a0 = bflo(rd0.x) - bflo(rs0.x), a1 = bfhi(rd0.x) - bfhi(rs0.x);
        float a2 = bflo(rd0.y) - bflo(rs0.y), a3 = bfhi(rd0.y) - bfhi(rs0.y);
        float a4 = bflo(rd0.z) - bflo(rs0.z), a5 = bfhi(rd0.z) - bfhi(rs0.z);
        float a6 = bflo(rd0.w) - bflo(rs0.w), a7 = bfhi(rd0.w) - bfhi(rs0.w);
        float b0 = bflo(rd1.x) - bflo(rs1.x), b1 = bfhi(rd1.x) - bfhi(rs1.x);
        float b2 = bflo(rd1.y) - bflo(rs1.y), b3 = bfhi(rd1.y) - bfhi(rs1.y);
        float b4 = bflo(rd1.z) - bflo(rs1.z), b5 = bfhi(rd1.z) - bfhi(rs1.z);
        float b6 = bflo(rd1.w) - bflo(rs1.w), b7 = bfhi(rd1.w) - bfhi(rs1.w);
        float c0 = bflo(rd2.x) - bflo(rs2.x), c1 = bfhi(rd2.x) - bfhi(rs2.x);
        float c2 = bflo(rd2.y) - bflo(rs2.y), c3 = bfhi(rd2.y) - bfhi(rs2.y);
        float c4 = bflo(rd2.z) - bflo(rs2.z), c5 = bfhi(rd2.z) - bfhi(rs2.z);
        float c6 = bflo(rd2.w) - bflo(rs2.w), c7 = bfhi(rd2.w) - bfhi(rs2.w);
        float g0 = bflo(rd3.x) - bflo(rs3.x), g1 = bfhi(rd3.x) - bfhi(rs3.x);
        float g2 = bflo(rd3.y) - bflo(rs3.y), g3 = bfhi(rd3.y) - bfhi(rs3.y);
        float g4 = bflo(rd3.z) - bflo(rs3.z), g5 = bfhi(rd3.z) - bfhi(rs3.z);
        float g6 = bflo(rd3.w) - bflo(rs3.w), g7 = bfhi(rd3.w) - bfhi(rs3.w);
        float ss0 = group8_sum(a0 * a0 + a1 * a1 + a2 * a2 + a3 * a3 +
                               a4 * a4 + a5 * a5 + a6 * a6 + a7 * a7);
        float ss1 = group8_sum(b0 * b0 + b1 * b1 + b2 * b2 + b3 * b3 +
                               b4 * b4 + b5 * b5 + b6 * b6 + b7 * b7);
        float ss2 = group8_sum(c0 * c0 + c1 * c1 + c2 * c2 + c3 * c3 +
                               c4 * c4 + c5 * c5 + c6 * c6 + c7 * c7);
        float ss3 = group8_sum(g0 * g0 + g1 * g1 + g2 * g2 + g3 * g3 +
                               g4 * g4 + g5 * g5 + g6 * g6 + g7 * g7);
        if (q8 == 0)
            lb += 0.5f * (att_csr[e0] * sqrtf(ss0 + 1e-12f) +
                          att_csr[e1] * sqrtf(ss1 + 1e-12f) +
                          att_csr[e2] * sqrtf(ss2 + 1e-12f) +
                          att_csr[e3] * sqrtf(ss3 + 1e-12f));
    }
    lb = wave_sum(lb);
    __shared__ float part[4];
    if (lane == 0) part[wib] = lb;
    __syncthreads();
    if (threadIdx.x == 0)
        atomicAdd(acc, part[0] + part[1] + part[2] + part[3]);
}

__global__ void k_finalize(const float* __restrict__ acc, float* __restrict__ out_loss) {
    out_loss[0] = acc[0] / (float)NNODES;
}

extern "C" void kernel_launch(void* const* d_in, const int* in_sizes, int n_in,
                              void* d_out, int out_size, void* d_ws, size_t ws_size,
                              hipStream_t stream) {
    const float* emb  = (const float*)d_in[0];
    const float* Wfc  = (const float*)d_in[1];
    const float* attn = (const float*)d_in[2];
    const int*   src  = (const int*)d_in[3];
    const int*   dst  = (const int*)d_in[4];
    float* out = (float*)d_out; // [N*H] h, then [1] loss

    char* p = (char*)d_ws;
    int*   cursor  = (int*)p;   p += (size_t)NNODES * 4;   // deg after fill
    float* lossAcc = (float*)p; p += 256;
    int*   row_ptr = (int*)p;   p += (size_t)(NNODES + 1) * 4;
    int*   bsums   = (int*)p;   p += (size_t)SCAN_NB * 4;
    float* wsv     = (float*)p; p += 64 * 4;
    float* wdv     = (float*)p; p += 64 * 4;
    float* zs0     = (float*)p; p += (size_t)NNODES * 4;
    float* zd0     = (float*)p; p += (size_t)NNODES * 4;
    float* zs1     = (float*)p; p += (size_t)NNODES * 4;
    float* zd1     = (float*)p; p += (size_t)NNODES * 4;
    float* laArr   = (float*)p; p += (size_t)NNODES * 4;
    float* att_csr = (float*)p; p += (size_t)NEDGES * 4;
    p = (char*)(((size_t)p + 255) & ~(size_t)255);
    u16*   padded  = (u16*)p;   p += (size_t)NNODES * CAP * 2;
    u16*   csr_src = (u16*)p;   p += (size_t)NEDGES * 2;
    u16*   dst_map = (u16*)p;   p += (size_t)NEDGES * 2;
    u16*   emb_bf  = (u16*)p;   p += (size_t)NNODES * HDIM * 2;
    u16*   h1_bf   = (u16*)p;   p += (size_t)NNODES * HDIM * 2;
    u16*   out_bf  = (u16*)p;   p += (size_t)NNODES * HDIM * 2;

    const int NB = (NNODES + 3) / 4;   // 12500 blocks, 1 node/wave

    k_init<<<SCAN_NB, 256, 0, stream>>>(cursor, lossAcc, Wfc, attn, wsv, wdv);
    k_fillx<<<NPART * FILL_SLICES, 256, 0, stream>>>((const int4*)src, (const int4*)dst,
                                                     cursor, padded);
    k_scan1z<<<NB, 256, 0, stream>>>(cursor, bsums, emb, wsv, wdv, emb_bf, zs0, zd0);
    k_scan3<<<SCAN_NB, SCAN_B, 0, stream>>>(cursor, bsums, row_ptr);

    // layer 1: gather emb_bf -> h1_bf, zs1/zd1; compact csr_src/dst_map
    k_layer<false, true, false, false, true><<<NB, 256, 0, stream>>>(
        emb_bf, emb, cursor, row_ptr, padded, zs0, zd0,
        att_csr, csr_src, dst_map, out /*unused*/, h1_bf, wsv, wdv, zs1, zd1, laArr);
    // layer 2: gather h1_bf -> out fp32 + out_bf; att; per-node loss_a
    k_layer<true, false, true, true, false><<<NB, 256, 0, stream>>>(
        h1_bf, emb, cursor, row_ptr, padded, zs1, zd1,
        att_csr, csr_src, dst_map, out, out_bf, wsv, wdv, zs0, zd0, laArr);

    k_loss<<<LOSS_GRID, 256, 0, stream>>>(laArr, out_bf, csr_src, dst_map, att_csr, lossAcc);
    k_finalize<<<1, 1, 0, stream>>>(lossAcc, out + (size_t)NNODES * HDIM);
}